// Round 1
// 86.868 us; speedup vs baseline: 1.0008x; 1.0008x over previous
//
#include <hip/hip_runtime.h>
#include <math.h>
#include <stdint.h>

#define NB 16
#define NL 128
#define NP 8192
#define THREADS 256
#define PPT 2            // protein atoms per thread (1 x v2 register block)
#define CHUNKS 16        // 8192 / (256 threads * 2 atoms)
#define LSPLIT 8         // ligand splits -> grid z
#define LPB 16           // ligands per block = 128/8

typedef float v2 __attribute__((ext_vector_type(2)));

__device__ __forceinline__ float fexp2(float x) { return __builtin_amdgcn_exp2f(x); }
__device__ __forceinline__ float frcp(float x)  { return __builtin_amdgcn_rcpf(x); }
__device__ __forceinline__ float frsq(float x)  { return __builtin_amdgcn_rsqf(x); }
__device__ __forceinline__ float fsqrt_(float x){ return __builtin_amdgcn_sqrtf(x); }
__device__ __forceinline__ v2 vfma(v2 a, v2 b, v2 c) { return __builtin_elementwise_fma(a, b, c); }

// one v2 block (2 protein atoms) of per-pair physics state
struct PState {
    v2 ppx, ppy, ppz, qP, rP, seP, xP0;
    v2 s1, s2, s3;
};

__device__ __forceinline__ void pair_step(PState& S, const float4 A0, const float4 A1)
{
    const v2 onev = (v2)1.0f;
    const v2 C1 = (v2)(-8.3333333e-6f);   // 200*tanh(v/200) ~ v*(1 + C1*v^2)
    const v2 K1 = (v2)(2.8853901f);       // 2*log2(e)
    const v2 K2 = (v2)(-34.624681f);      // -24*log2(e)

    v2 dx = (v2)A0.x - S.ppx;
    v2 dy = (v2)A0.y - S.ppy;
    v2 dz = (v2)A0.z - S.ppz;
    v2 ds = vfma(dx, dx, vfma(dy, dy, vfma(dz, dz, (v2)1e-8f)));
    v2 dist; dist.x = fsqrt_(ds.x); dist.y = fsqrt_(ds.y);

    v2 sigma = (v2)A1.x + S.rP;
    v2 sigsq = sigma * sigma;
    v2 sd2 = vfma(sigsq, (v2)2.0f, ds);           // ds + 2*sigma^2
    v2 inv; inv.x = frsq(sd2.x); inv.y = frsq(sd2.y);

    // e_elec = 200*tanh(v/200) ~ v*(1 + C1*v^2); |v|<=32 -> err<=1.4e-3
    v2 v = ((v2)A0.w * S.qP) * inv;
    v2 w = v * v;
    v2 e_elec = v * vfma(w, C1, onev);

    // e_vdw_raw in [-0.14,0] always -> grad path == clipped log path == ev
    v2 inv2 = inv * inv;
    v2 r2 = sigsq * inv2;
    v2 r6 = r2 * r2 * r2;
    v2 t126 = vfma(r6, r6, -r6);                  // r12 - r6
    v2 ev = ((v2)A1.y * S.seP) * t126;            // 4*eps_ij*(r12-r6)
    v2 addend = e_elec + ev;

    // dm = sigmoid((12-dist)*2); hsa = 1/(1+(ds/16)^2); shared rcp.
    // exp2 overflow -> A=inf -> rr=0 -> dm=0 (correct limit, no NaN).
    v2 m = vfma(dist, K1, K2);
    v2 A; A.x = fexp2(m.x); A.y = fexp2(m.y);
    A = A + onev;
    v2 tq = ds * 0.0625f;
    v2 Bh = vfma(tq, tq, onev);
    v2 AB = A * Bh;
    v2 rr; rr.x = frcp(AB.x); rr.y = frcp(AB.y);
    v2 dm = Bh * rr;

    S.s1 = vfma(addend, dm, S.s1);
    S.s2 = vfma((v2)A1.z, rr, S.s2);
    v2 ov = __builtin_elementwise_max(vfma(sigma, (v2)0.6f, -dist), (v2)0.0f);
    S.s3 = vfma(ov, ov, S.s3);
}

__device__ __forceinline__ void load_pstate(
    PState& S, const float* pos_P, const float* q_P, const float* x_P,
    int pb0, int stride)
{
    const int pbA = pb0, pbB = pb0 + stride;
    S.ppx.x = pos_P[pbA * 3 + 0]; S.ppx.y = pos_P[pbB * 3 + 0];
    S.ppy.x = pos_P[pbA * 3 + 1]; S.ppy.y = pos_P[pbB * 3 + 1];
    S.ppz.x = pos_P[pbA * 3 + 2]; S.ppz.y = pos_P[pbB * 3 + 2];
    S.qP.x  = q_P[pbA];           S.qP.y  = q_P[pbB];
    const float4 xa = ((const float4*)x_P)[pbA];
    const float4 xb = ((const float4*)x_P)[pbB];
    S.rP.x  = 1.7f * xa.x + 1.55f * xa.y + 1.52f * xa.z + 1.8f * xa.w;
    S.rP.y  = 1.7f * xb.x + 1.55f * xb.y + 1.52f * xb.z + 1.8f * xb.w;
    S.seP.x = fsqrt_(0.1f * xa.x + 0.10f * xa.y + 0.15f * xa.z + 0.2f * xa.w);
    S.seP.y = fsqrt_(0.1f * xb.x + 0.10f * xb.y + 0.15f * xb.z + 0.2f * xb.w);
    S.xP0.x = xa.x; S.xP0.y = xb.x;
    S.s1 = (v2)0.0f; S.s2 = (v2)0.0f; S.s3 = (v2)0.0f;
}

// ---- kernel 1: fused ligand prep (per-block, redundant, trivial) + main loop ----
// 64-VGPR target: 8 workgroups/CU -> 8 waves/SIMD to hide trans-chain latency.
__global__ __launch_bounds__(THREADS, 8) void physics_main(
    const float* __restrict__ pos_L, const float* __restrict__ pos_P,
    const float* __restrict__ q_L,   const float* __restrict__ q_P,
    const float* __restrict__ x_L,   const float* __restrict__ x_P,
    const float* __restrict__ vdw_radii, const float* __restrict__ eps_tbl,
    float* __restrict__ partial)
{
    const int b     = blockIdx.y;
    const int chunk = blockIdx.x;
    const int z     = blockIdx.z;
    const int tid   = threadIdx.x;

    // ligand tile: [i][0]=(px,py,pz,aq)  [i][1]=(rad,se4,x0,0)
    __shared__ float4 lig[LPB][2];
    __shared__ float red[4][3];

    if (tid < LPB) {
        const int base = b * NL + z * LPB + tid;
        float px = pos_L[base * 3 + 0];
        float py = pos_L[base * 3 + 1];
        float pz = pos_L[base * 3 + 2];
        float aq = 83.015f * q_L[base];       // 332.06 / 4
        float rad = 0.0f, ep = 0.0f;
        #pragma unroll
        for (int j = 0; j < 9; ++j) {
            float v = x_L[base * 9 + j];
            rad = fmaf(v, vdw_radii[j], rad);
            ep  = fmaf(v, eps_tbl[j],  ep);
        }
        float se4 = 4.0f * fsqrt_(fmaxf(ep, 0.0f));   // 4*sqrt(relu(epsL))
        float x0  = x_L[base * 9 + 0];
        lig[tid][0] = make_float4(px, py, pz, aq);
        lig[tid][1] = make_float4(rad, se4, x0, 0.0f);
    }

    const int p0  = chunk * (THREADS * PPT) + tid;
    const int pb0 = b * NP + p0;

    PState SA;
    load_pstate(SA, pos_P, q_P, x_P, pb0, THREADS);

    __syncthreads();

    #pragma unroll 4
    for (int i = 0; i < LPB; ++i) {
        const float4 A0 = lig[i][0];      // uniform LDS -> broadcast
        const float4 A1 = lig[i][1];
        pair_step(SA, A0, A1);
    }

    v2 s2pA = SA.s2 * SA.xP0;
    float s1 = SA.s1.x + SA.s1.y;
    float s2 = s2pA.x + s2pA.y;
    float s3 = SA.s3.x + SA.s3.y;

    #pragma unroll
    for (int off = 32; off > 0; off >>= 1) {
        s1 += __shfl_down(s1, off);
        s2 += __shfl_down(s2, off);
        s3 += __shfl_down(s3, off);
    }
    const int lane = tid & 63;
    const int wid  = tid >> 6;
    if (lane == 0) { red[wid][0] = s1; red[wid][1] = s2; red[wid][2] = s3; }
    __syncthreads();
    if (tid == 0) {
        float r0 = red[0][0] + red[1][0] + red[2][0] + red[3][0];
        float r1 = red[0][1] + red[1][1] + red[2][1] + red[3][1];
        float r2_ = red[0][2] + red[1][2] + red[2][2] + red[3][2];
        float* dst = partial + ((size_t)((b * CHUNKS + chunk) * LSPLIT + z)) * 4;
        dst[0] = r0; dst[1] = r1; dst[2] = r2_;
    }
}

// ---- kernel 2: finalize, 16 lanes per batch (128 partials/batch) ----
__global__ __launch_bounds__(256) void physics_final(
    const float* __restrict__ partial, float* __restrict__ out)
{
    const int tid = threadIdx.x;
    if (tid == 0) out[2 * NB] = 2.0f;   // ALPHA
    const int b = tid >> 4;
    const int j = tid & 15;
    float s1 = 0.0f, s2 = 0.0f, s3 = 0.0f;
    const int NPART = CHUNKS * LSPLIT;   // 128 per batch
    #pragma unroll
    for (int k = 0; k < NPART / 16; ++k) {
        const float* src = partial + ((size_t)(b * NPART + j * (NPART / 16) + k)) * 4;
        s1 += src[0]; s2 += src[1]; s3 += src[2];
    }
    #pragma unroll
    for (int off = 8; off > 0; off >>= 1) {
        s1 += __shfl_down(s1, off, 16);
        s2 += __shfl_down(s2, off, 16);
        s3 += __shfl_down(s3, off, 16);
    }
    if (j == 0) {
        const float TG100 = 95.25741268224334f;   // sigmoid(3)*100
        float e_pauli = TG100 * s3;
        float e_hsa5  = -2.5f * s2;               // 5 * (-0.5 * S2)
        float e_raw = s1 + e_hsa5 + e_pauli;
        if (e_raw != e_raw) e_raw = 0.0f;
        float e_hard_log = fminf(e_pauli, 10000.0f);
        float e_soft_log = fminf(fmaxf(s1 + e_hsa5, -500.0f), 5000.0f);  // s4==s1
        float log_energy = fminf(e_soft_log + e_hard_log, 1000000.0f);
        out[b]              = e_raw;
        out[NB + b]         = e_hard_log;
        out[2 * NB + 1 + b] = log_energy;
    }
}

extern "C" void kernel_launch(void* const* d_in, const int* in_sizes, int n_in,
                              void* d_out, int out_size, void* d_ws, size_t ws_size,
                              hipStream_t stream)
{
    const float* pos_L = (const float*)d_in[0];
    const float* pos_P = (const float*)d_in[1];
    const float* q_L   = (const float*)d_in[2];
    const float* q_P   = (const float*)d_in[3];
    const float* x_L   = (const float*)d_in[4];
    const float* x_P   = (const float*)d_in[5];
    const float* vdw   = (const float*)d_in[6];
    const float* epst  = (const float*)d_in[7];
    float* out = (float*)d_out;
    float* partial = (float*)d_ws;     // 16*128*4 floats = 32 KB

    dim3 grid(CHUNKS, NB, LSPLIT);
    physics_main<<<grid, THREADS, 0, stream>>>(pos_L, pos_P, q_L, q_P, x_L, x_P,
                                               vdw, epst, partial);
    physics_final<<<1, 256, 0, stream>>>(partial, out);
}